// Round 13
// baseline (103.096 us; speedup 1.0000x reference)
//
#include <hip/hip_runtime.h>

// Chamfer via MFMA half-distance matrix, v9: BARRIER-FREE, LDS-FREE.
// R12 post-mortem closed the model: per-SIMD pipe demands are MFMA 13.7us
// (1024 mfma x 32cyc/SIMD-pipe; MfmaUtil 27% x 48.9us = 13.2 ✓) and VALU
// ~14us (min3) -- the 48.5us wall across R9/R11/R12 is the barrier-locked
// staging loop running the two pipes at ~27% overlap: 32 syncthreads/block,
// each draining vmcnt/lgkmcnt over 4 lockstep waves, chop execution into
// ~600cyc serial segments. sched_barrier fences didn't change codegen
// (VGPR 100, dur 48.96 == R9).
// R13: the XCD swizzle already makes fragment panels L2-resident (FETCH
// 2.9MB), so LDS staging is pure overhead (Common-mistake #7). Remove LDS
// and ALL barriers; waves free-run reading B-frags straight from L2 via
// coalesced dwordx4 + 1-iter register prefetch (T14). NAF=2 (rmn 32 regs,
// VGPR ~140 -> 3 waves/SIMD), DSPLIT=4 -> 2048 blocks oversupply.
// Tells: LDS_Block_Size 0; MfmaUtil -> 50-70; WRITE stays ~4MB (no spill).
//
// Math (R5-R12 verified, absmax 0.0): h = 0.5|p|^2 + 0.5|t|^2 - p.t = d/2
// via K=16 of v_mfma_f32_32x32x16_bf16 with bf16 hi/lo split:
//   A(p): half0 [xh xh xl yh yh yl zh zh]  half1 [zl ph pl 1 1 0 0 0]
//   B(t): half0 [nxh nxl nxh nyh nyl nyh nzh nzl] half1 [nzh 1 1 hh hl 0 0 0]
// C layout (m74/m101): col=lane&31, row=(reg&3)+8*(reg>>2)+4*(lane>>5).
// Both directions run as row-min MFMA passes (dir1 swaps A/B roles).

typedef float f32x16 __attribute__((ext_vector_type(16)));
typedef short bf16x8 __attribute__((ext_vector_type(8)));

constexpr int BATCH  = 8;
constexpr int NPTS   = 8192;
constexpr int BLOCK  = 256;            // 4 independent waves (no barriers)
constexpr int QTILE  = 256;            // A-points per block (64 per wave)
constexpr int NAF    = 2;              // A-frags per wave
constexpr int QB     = NPTS / QTILE;   // 32 A-blocks per direction
constexpr int DSPLIT = 4;              // db split per direction
constexpr int DBR    = NPTS / DSPLIT;  // 2048 db points per block
constexpr int NT     = DBR / 32;       // 64 B-tiles of 32 points
constexpr int NBLK   = QB * BATCH * 2 * DSPLIT;   // 2048

// workspace: fragT [B][NPTS][2] uint4 (2MB) | fragS same (2MB)
//            | mins [2][B][NPTS] u32 (512KB)
constexpr size_t FRAG_N = (size_t)BATCH * NPTS * 2;   // uint4s per array
constexpr size_t SM_N   = (size_t)BATCH * NPTS;       // u32 per direction

static __device__ __forceinline__ float fmin3(float a, float b, float c) {
    return fminf(fminf(a, b), c);   // v_min3_f32
}
static __device__ __forceinline__ unsigned short bf16h(float f) {
    unsigned int u = __float_as_uint(f);
    u += 0x7fffu + ((u >> 16) & 1u);           // RNE
    return (unsigned short)(u >> 16);
}
static __device__ __forceinline__ float bf16tof(unsigned short h) {
    return __uint_as_float(((unsigned int)h) << 16);
}
static __device__ __forceinline__ unsigned int pack2(unsigned short a, unsigned short b) {
    return (unsigned int)a | ((unsigned int)b << 16);
}

static __device__ __forceinline__ void make_bfrag(float px, float py, float pz,
                                                  uint4& p0, uint4& p1) {
    const unsigned short one = bf16h(1.0f);
    float nx = -px, ny = -py, nz = -pz;
    float ht = 0.5f * fmaf(px, px, fmaf(py, py, pz * pz));
    unsigned short nxh = bf16h(nx), nxl = bf16h(nx - bf16tof(nxh));
    unsigned short nyh = bf16h(ny), nyl = bf16h(ny - bf16tof(nyh));
    unsigned short nzh = bf16h(nz), nzl = bf16h(nz - bf16tof(nzh));
    unsigned short hh = bf16h(ht),  hl = bf16h(ht - bf16tof(hh));
    p0 = make_uint4(pack2(nxh, nxl), pack2(nxh, nyh),
                    pack2(nyl, nyh), pack2(nzh, nzl));
    p1 = make_uint4(pack2(nzh, one), pack2(one, hh),
                    pack2(hl, 0), 0u);
}

// ---- prep: both arrays -> B-fragments; init mins; zero out ----
__global__ __launch_bounds__(BLOCK) void chamfer_prep(
    const float* __restrict__ src, const float* __restrict__ tgt,
    uint4* __restrict__ fragS, uint4* __restrict__ fragT,
    unsigned int* __restrict__ mins, float* __restrict__ out)
{
    const int i = blockIdx.x * BLOCK + threadIdx.x;   // [0, B*NPTS)
    uint4 p0, p1;
    const float* tp = tgt + (size_t)i * 3;
    make_bfrag(tp[0], tp[1], tp[2], p0, p1);
    fragT[2 * i + 0] = p0;
    fragT[2 * i + 1] = p1;
    const float* sp = src + (size_t)i * 3;
    make_bfrag(sp[0], sp[1], sp[2], p0, p1);
    fragS[2 * i + 0] = p0;
    fragS[2 * i + 1] = p1;
    mins[i]        = 0x7f7f7f7fu;
    mins[SM_N + i] = 0x7f7f7f7fu;
    if (i < BATCH) out[i] = 0.0f;
}

__global__ __launch_bounds__(BLOCK, 2) void chamfer_nn(
    const float* __restrict__ src, const float* __restrict__ tgt,
    const uint4* __restrict__ fragS, const uint4* __restrict__ fragT,
    unsigned int* __restrict__ mins)
{
    const int tid  = threadIdx.x;
    const int lane = tid & 63;
    const int w    = tid >> 6;
    const int half = lane >> 5;
    const int l31  = lane & 31;

    // ---- XCD-panel swizzle (bijective on [0,2048)) ----
    // panel = (b,dir,ds) in [0,64); its 32 qb-siblings share lin&7 -> same
    // XCD under mod-8 round-robin -> 64KB panel L2-resident (validated
    // R10-R12: FETCH 17.3 -> 2.9 MB).
    const int lin  = blockIdx.x;
    const int rest = lin >> 3;                        // [0,256)
    const int qb   = rest & 31;                       // [0,32)
    const int p    = ((rest >> 5) << 3) | (lin & 7);  // panel [0,64)
    const int b    = p & 7;
    const int z    = p >> 3;                          // [0,8)
    const int dir  = z >> 2;   // 0: A=src,B=tgt ; 1: swapped
    const int ds   = z & 3;

    const float* P  = dir ? tgt : src;      // A-side raw points
    const uint4* FB = dir ? fragS : fragT;  // B-side fragments

    // ---- build NAF A-fragments (A-points qbase + g*32 + l31) ----
    const unsigned short one = bf16h(1.0f);
    bf16x8 af[NAF];
#pragma unroll
    for (int g = 0; g < NAF; g++) {
        const int q = qb * QTILE + w * (32 * NAF) + g * 32 + l31;
        const float* qp = P + ((size_t)b * NPTS + q) * 3;
        float qx = qp[0], qy = qp[1], qz = qp[2];
        float hq = 0.5f * fmaf(qx, qx, fmaf(qy, qy, qz * qz));
        unsigned short xh = bf16h(qx), xl = bf16h(qx - bf16tof(xh));
        unsigned short yh = bf16h(qy), yl = bf16h(qy - bf16tof(yh));
        unsigned short zh = bf16h(qz), zl = bf16h(qz - bf16tof(zh));
        unsigned short qh = bf16h(hq), ql = bf16h(hq - bf16tof(qh));
        bf16x8 a;
        if (half == 0) {
            a[0] = (short)xh; a[1] = (short)xh; a[2] = (short)xl;
            a[3] = (short)yh; a[4] = (short)yh; a[5] = (short)yl;
            a[6] = (short)zh; a[7] = (short)zh;
        } else {
            a[0] = (short)zl; a[1] = (short)qh; a[2] = (short)ql;
            a[3] = (short)one; a[4] = (short)one;
            a[5] = 0; a[6] = 0; a[7] = 0;
        }
        af[g] = a;
    }

    float rmn0[16], rmn1[16];
#pragma unroll
    for (int r = 0; r < 16; r++) { rmn0[r] = 3.4e38f; rmn1[r] = 3.4e38f; }
    const f32x16 zz = {};   // persistent zero VGPRs, C input for all MFMAs

    // per-lane B pointer: element 2*(t*32+l31)+half = 64*t + (2*l31+half).
    // Wave covers a contiguous 1KB line-set per tile -> fully coalesced,
    // L2-resident by swizzle. No LDS, no barriers: waves free-run.
    const uint4* gp = FB + ((size_t)b * NPTS + (size_t)ds * DBR) * 2
                         + 2 * l31 + half;

    // register prefetch, 1-iteration distance (T14)
    uint4 c0 = gp[0], c1 = gp[64];
    for (int t = 0; t < NT; t += 2) {
        bf16x8 b0 = __builtin_bit_cast(bf16x8, c0);
        bf16x8 b1 = __builtin_bit_cast(bf16x8, c1);
        if (t + 2 < NT) {                   // issue next pair early
            c0 = gp[64 * (t + 2)];
            c1 = gp[64 * (t + 3)];
        }
        f32x16 a00 = __builtin_amdgcn_mfma_f32_32x32x16_bf16(af[0], b0, zz, 0, 0, 0);
        f32x16 a01 = __builtin_amdgcn_mfma_f32_32x32x16_bf16(af[0], b1, zz, 0, 0, 0);
        f32x16 a10 = __builtin_amdgcn_mfma_f32_32x32x16_bf16(af[1], b0, zz, 0, 0, 0);
        f32x16 a11 = __builtin_amdgcn_mfma_f32_32x32x16_bf16(af[1], b1, zz, 0, 0, 0);
#pragma unroll
        for (int r = 0; r < 16; r++) {
            rmn0[r] = fmin3(rmn0[r], a00[r], a01[r]);   // row-min over db
            rmn1[r] = fmin3(rmn1[r], a10[r], a11[r]);
        }
    }

    // ---- epilogue: fold cols 32->1 in-wave, global atomicMin merge ----
    unsigned int* M = mins + ((size_t)dir * BATCH + b) * NPTS;
    const int qbase = qb * QTILE + w * (32 * NAF);
#pragma unroll
    for (int r = 0; r < 16; r++) {
        float a = rmn0[r], bv = rmn1[r];
#pragma unroll
        for (int off = 16; off > 0; off >>= 1) {
            a  = fminf(a,  __shfl_xor(a,  off, 64));
            bv = fminf(bv, __shfl_xor(bv, off, 64));
        }
        if (l31 == 0) {   // lanes 0 (half0 row) and 32 (half1 row)
            const int row = (r & 3) + 8 * (r >> 2) + 4 * half;
            atomicMin(&M[qbase + row],      __float_as_uint(fmaxf(a,  0.0f)));
            atomicMin(&M[qbase + 32 + row], __float_as_uint(fmaxf(bv, 0.0f)));
        }
    }
}

// ---- final: sum mins[2][B][NPTS] (512KB), atomicAdd into out ----
__global__ __launch_bounds__(BLOCK) void chamfer_final(
    const unsigned int* __restrict__ mins, float* __restrict__ out)
{
    const int seg = blockIdx.x;   // 4 segments of 2048
    const int b   = blockIdx.y;
    const int tid = threadIdx.x;
    float acc = 0.0f;
#pragma unroll
    for (int k = 0; k < 8; k++) {
        const size_t i = (size_t)b * NPTS + seg * 2048 + k * BLOCK + tid;
        acc += __uint_as_float(mins[i]) + __uint_as_float(mins[SM_N + i]);
    }
    for (int off = 32; off > 0; off >>= 1) acc += __shfl_down(acc, off, 64);
    __shared__ float wsum[4];
    if ((tid & 63) == 0) wsum[tid >> 6] = acc;
    __syncthreads();
    if (tid == 0)   // stored values are half-distances: d = 2h
        atomicAdd(&out[b],
                  (wsum[0] + wsum[1] + wsum[2] + wsum[3]) * (2.0f / (float)NPTS));
}

extern "C" void kernel_launch(void* const* d_in, const int* in_sizes, int n_in,
                              void* d_out, int out_size, void* d_ws, size_t ws_size,
                              hipStream_t stream) {
    const float* src = (const float*)d_in[0];  // [B, N, 3]
    const float* tgt = (const float*)d_in[1];  // [B, M, 3]
    float* out = (float*)d_out;                // [B]

    uint4* fragT        = (uint4*)d_ws;                     // 2 MB
    uint4* fragS        = fragT + FRAG_N;                   // 2 MB
    unsigned int* mins  = (unsigned int*)(fragS + FRAG_N);  // 512 KB

    chamfer_prep<<<BATCH * NPTS / BLOCK, BLOCK, 0, stream>>>(
        src, tgt, fragS, fragT, mins, out);
    chamfer_nn<<<NBLK, BLOCK, 0, stream>>>(
        src, tgt, fragS, fragT, mins);
    chamfer_final<<<dim3(4, BATCH), BLOCK, 0, stream>>>(mins, out);
}